// Round 1
// baseline (219.279 us; speedup 1.0000x reference)
//
#include <hip/hip_runtime.h>
#include <hip/hip_bf16.h>

#define N_NODES 50000
#define N_EDGES 800000
#define D 64
#define N_REL 500
#define N_TIME 1000
#define SLOTS 64   // per-node edge bucket capacity (max observed degree ~35)
#define NODE_BLOCKS ((N_NODES + 63) / 64)   // 782
#define REL_BLOCKS  ((N_REL + 63) / 64)     // 8

// Two-phase build parameters
#define NBUCKET 8                 // one coarse bucket per XCD
#define NODES_PER_BUCKET 6250     // 8 x 6250 = 50000, even 3.2 MB payload regions
#define STAGE_CAP 131072          // per-bucket staging capacity (mean 100K, +100 sigma)
#define BIN_CAP 256               // LDS bin capacity per tile (mean 128, +12 sigma)
#define TILE 1024                 // edges per bin_kernel block (4/thread)
#define PASS2_CHUNKS 128          // chunks per bucket in scatter_kernel

__device__ __forceinline__ float bf2f(unsigned short u) {
    union { unsigned int i; float f; } v;
    v.i = ((unsigned int)u) << 16;
    return v.f;
}

// ---------------------------------------------------------------------------
// K1: scalar attention projections + bf16 cast of x.  One wave per row.
// ---------------------------------------------------------------------------
__global__ void proj_kernel(const float* __restrict__ x,
                            const float* __restrict__ rel,
                            const float* __restrict__ tim,
                            const float* __restrict__ ah,
                            const float* __restrict__ at,
                            const float* __restrict__ ar,
                            const float* __restrict__ ats,
                            float* __restrict__ h_att, float* __restrict__ t_att,
                            float* __restrict__ r_att, float* __restrict__ ts_att,
                            unsigned short* __restrict__ x_bf) {
    int wave = (blockIdx.x * blockDim.x + threadIdx.x) >> 6;
    int lane = threadIdx.x & 63;
    const int total = N_NODES + N_REL + N_TIME;
    if (wave >= total) return;
    if (wave < N_NODES) {
        float xv = x[wave * D + lane];
        __hip_bfloat16 b = __float2bfloat16(xv);
        x_bf[wave * D + lane] = *(unsigned short*)&b;
        float s1 = xv * ah[lane];
        float s2 = xv * at[lane];
        for (int off = 32; off; off >>= 1) {
            s1 += __shfl_down(s1, off);
            s2 += __shfl_down(s2, off);
        }
        if (lane == 0) { h_att[wave] = s1; t_att[wave] = s2; }
    } else if (wave < N_NODES + N_REL) {
        int r = wave - N_NODES;
        float v = rel[r * D + lane] * ar[lane];
        for (int off = 32; off; off >>= 1) v += __shfl_down(v, off);
        if (lane == 0) r_att[r] = v;
    } else {
        int t = wave - N_NODES - N_REL;
        float v = tim[t * D + lane] * ats[lane];
        for (int off = 32; off; off >>= 1) v += __shfl_down(v, off);
        if (lane == 0) ts_att[t] = v;
    }
}

// ---------------------------------------------------------------------------
// K2 (legacy fallback): single-pass scatter build.  8x write amplification
// (50 MB at ~1 TB/s random-line write ceiling, 56 us).  Used only when the
// workspace can't fit the two-phase staging area.
// ---------------------------------------------------------------------------
__global__ void build_kernel(const int* __restrict__ src, const int* __restrict__ dst,
                             const int* __restrict__ etype, const int* __restrict__ etime,
                             const float* __restrict__ h_att, const float* __restrict__ t_att,
                             const float* __restrict__ r_att, const float* __restrict__ ts_att,
                             int* __restrict__ cnt, int2* __restrict__ payload) {
    int e = blockIdx.x * blockDim.x + threadIdx.x;
    if (e >= N_EDGES) return;
    int s = src[e], d = dst[e], r = etype[e], t = etime[e];
    float lg = h_att[s] - t_att[d] + r_att[r] + ts_att[t];
    float lr = lg > 0.f ? lg : 0.1f * lg;
    float ex = __expf(lr);
    unsigned exb = __float_as_uint(ex);
    int2 pl;
    pl.x = (int)((exb & ~7u) | (unsigned)(s & 7));
    pl.y = (int)(((unsigned)(s >> 3) << 19) | ((unsigned)r << 10) | (unsigned)t);
    int pos = atomicAdd(&cnt[d], 1);
    if (pos < SLOTS) payload[(d << 6) + pos] = pl;   // drop, never corrupt
}

// ---------------------------------------------------------------------------
// K2a: bin edges into 8 coarse dst-range buckets with COALESCED writes.
// Per block: 1024 edges -> LDS bins (mean 128/bin) -> one cursor atomicAdd
// per bin -> contiguous int4 flush.  Record = {payload.x, payload.y, dst, 0}.
// Statistical overflow guard falls back to a direct (uncoalesced) append.
// ---------------------------------------------------------------------------
__global__ __launch_bounds__(256)
void bin_kernel(const int* __restrict__ src, const int* __restrict__ dst,
                const int* __restrict__ etype, const int* __restrict__ etime,
                const float* __restrict__ h_att, const float* __restrict__ t_att,
                const float* __restrict__ r_att, const float* __restrict__ ts_att,
                int* __restrict__ bucket_cursor, int4* __restrict__ stage) {
    __shared__ int4 bins[NBUCKET][BIN_CAP];   // 32 KB
    __shared__ int bcnt[NBUCKET];
    __shared__ int bbase[NBUCKET];
    int t = threadIdx.x;
    if (t < NBUCKET) bcnt[t] = 0;
    __syncthreads();

    int e0 = blockIdx.x * TILE;
    for (int j = 0; j < 4; j++) {
        int e = e0 + j * 256 + t;
        if (e < N_EDGES) {
            int s = src[e], d = dst[e], r = etype[e], tt = etime[e];
            float lg = h_att[s] - t_att[d] + r_att[r] + ts_att[tt];
            float lr = lg > 0.f ? lg : 0.1f * lg;
            float ex = __expf(lr);
            unsigned exb = __float_as_uint(ex);
            int4 rec;
            rec.x = (int)((exb & ~7u) | (unsigned)(s & 7));
            rec.y = (int)(((unsigned)(s >> 3) << 19) | ((unsigned)r << 10) | (unsigned)tt);
            rec.z = d;
            rec.w = 0;
            int k = (int)((unsigned)d / NODES_PER_BUCKET);
            int pos = atomicAdd(&bcnt[k], 1);
            if (pos < BIN_CAP) {
                bins[k][pos] = rec;
            } else {                               // statistically ~never
                int g = atomicAdd(&bucket_cursor[k], 1);
                if (g < STAGE_CAP) stage[k * STAGE_CAP + g] = rec;
            }
        }
    }
    __syncthreads();
    if (t < NBUCKET) {
        int c = bcnt[t] < BIN_CAP ? bcnt[t] : BIN_CAP;
        bbase[t] = atomicAdd(&bucket_cursor[t], c);
        bcnt[t] = c;
    }
    __syncthreads();
    for (int k = 0; k < NBUCKET; k++) {
        int c = bcnt[k];
        int base = bbase[k];
        for (int idx = t; idx < c; idx += 256) {
            int g = base + idx;
            if (g < STAGE_CAP) stage[k * STAGE_CAP + g] = bins[k][idx];
        }
    }
}

// ---------------------------------------------------------------------------
// K2b: per-bucket scatter into the payload slot array.  bucket = blockIdx % 8
// pins each bucket's blocks to one XCD (round-robin heuristic), so the
// scattered 8B stores land in a 3.2 MB L2-resident window and a node's ~16
// writes MERGE into ~2 lines before writeback.  All 128 chunks of a bucket
// are co-resident, so merge windows overlap in time.  cnt[] doubles as the
// per-node position cursor and ends at the exact degree K3 expects.
// ---------------------------------------------------------------------------
__global__ __launch_bounds__(256)
void scatter_kernel(const int* __restrict__ bucket_cursor,
                    const int4* __restrict__ stage,
                    int* __restrict__ cnt, int2* __restrict__ payload) {
    int b = blockIdx.x & (NBUCKET - 1);
    int chunk = blockIdx.x >> 3;
    int n = bucket_cursor[b];
    if (n > STAGE_CAP) n = STAGE_CAP;
    int ch = (n + PASS2_CHUNKS - 1) / PASS2_CHUNKS;
    int start = chunk * ch;
    int end = start + ch;
    if (end > n) end = n;
    for (int idx = start + (int)threadIdx.x; idx < end; idx += 256) {
        int4 rec = stage[b * STAGE_CAP + idx];
        int d = rec.z;
        int pos = atomicAdd(&cnt[d], 1);
        if (pos < SLOTS) payload[(d << 6) + pos] = make_int2(rec.x, rec.y);
    }
}

// ---------------------------------------------------------------------------
// K3: per-dst-node softmax + weighted gather-aggregate.  One wave per node.
// Phase A: lane = edge slot; ONE coalesced 8B payload load, UNSIGNED decode,
// butterfly den.  Phase B: quarter-wave per edge; x gathered bf16 (128 B/row),
// rel/tim fp32 (L2-hot).  agg row (stride 128 floats) OVERLAYS this node's
// payload region -- safe: payload fully consumed into registers first.
// ---------------------------------------------------------------------------
__global__ void node_gather_kernel(const unsigned short* __restrict__ x_bf,
                                   const float* __restrict__ rel,
                                   const float* __restrict__ tim,
                                   const int* __restrict__ cnt,
                                   const int2* __restrict__ payload,
                                   float* __restrict__ agg) {
    int d = (blockIdx.x * blockDim.x + threadIdx.x) >> 6;
    int lane = threadIdx.x & 63;
    if (d >= N_NODES) return;
    int deg = cnt[d];
    if (deg > SLOTS) deg = SLOTS;

    // Phase A: coalesced payload read + unsigned decode
    int s_l = 0, r_l = 0, t_l = 0;
    float ex = 0.f;
    if (lane < deg) {
        int2 pl = payload[(d << 6) + lane];
        unsigned px = (unsigned)pl.x;
        unsigned py = (unsigned)pl.y;
        ex = __uint_as_float(px & ~7u);
        s_l = (int)(((py >> 19) << 3) | (px & 7u));
        r_l = (int)((py >> 10) & 511u);
        t_l = (int)(py & 1023u);
    }
    float den = ex;
    for (int off = 32; off; off >>= 1) den += __shfl_xor(den, off);
    float att_l = (lane < deg) ? ex / den : 0.f;

    // Phase B: quarter-wave per edge
    int qw = lane >> 4;
    int ql = lane & 15;
    float4 acc = make_float4(0.f, 0.f, 0.f, 0.f);
    for (int i = 0; i < deg; i += 4) {
        int ei = i + qw;                  // < 64 always
        int s = __shfl(s_l, ei);
        int r = __shfl(r_l, ei);
        int t = __shfl(t_l, ei);
        float att = __shfl(att_l, ei);    // 0 if ei >= deg
        float4  te = *(const float4*)(tim + t * D + ql * 4);
        ushort4 xb = *(const ushort4*)(x_bf + s * D + ql * 4);
        float4  rl = *(const float4*)(rel + r * D + ql * 4);
        acc.x += att * (bf2f(xb.x) + te.x) * (rl.x + te.x);
        acc.y += att * (bf2f(xb.y) + te.y) * (rl.y + te.y);
        acc.z += att * (bf2f(xb.z) + te.z) * (rl.z + te.z);
        acc.w += att * (bf2f(xb.w) + te.w) * (rl.w + te.w);
    }
    for (int off = 16; off <= 32; off <<= 1) {
        acc.x += __shfl_xor(acc.x, off);
        acc.y += __shfl_xor(acc.y, off);
        acc.z += __shfl_xor(acc.z, off);
        acc.w += __shfl_xor(acc.w, off);
    }
    if (qw == 0)
        *(float4*)(agg + (d << 7) + ql * 4) = acc;   // stride 128 (overlay)
}

// ---------------------------------------------------------------------------
// K4: epilogue GEMMs, register-blocked 4x4 per thread, 64-row tiles.
//   blocks [0, NODE_BLOCKS):  out[r] = agg[r] @ trans_w + x[r] @ loop_w
//   blocks [NODE_BLOCKS, +REL_BLOCKS): out[N_NODES+r] = rel[r] @ w_rel
// Weights in LDS (32 KB); A-operands straight from global.  agg rows at
// stride 128 floats (payload overlay).
// ---------------------------------------------------------------------------
__global__ __launch_bounds__(256, 4)
void out_gemm_kernel(const float* __restrict__ agg,
                     const float* __restrict__ x,
                     const float* __restrict__ rel,
                     const float* __restrict__ trans_w,
                     const float* __restrict__ loop_w,
                     const float* __restrict__ w_rel,
                     float* __restrict__ out) {
    __shared__ float Wa[D * D];
    __shared__ float Wb[D * D];
    int t = threadIdx.x;
    bool nodeb = blockIdx.x < NODE_BLOCKS;

    for (int j = 0; j < 4; j++) {
        int idx = (t + 256 * j) * 4;
        if (nodeb) {
            *(float4*)(Wa + idx) = *(const float4*)(trans_w + idx);
            *(float4*)(Wb + idx) = *(const float4*)(loop_w + idx);
        } else {
            *(float4*)(Wa + idx) = *(const float4*)(w_rel + idx);
        }
    }
    __syncthreads();

    int lane = t & 63;
    int wv = t >> 6;
    int c4 = (lane & 15) << 2;
    int r0 = wv * 16 + (lane >> 4) * 4;

    float acc[4][4];
    for (int i = 0; i < 4; i++)
        for (int c = 0; c < 4; c++) acc[i][c] = 0.f;

    if (nodeb) {
        int row0 = blockIdx.x * 64;
        for (int k = 0; k < D; k += 4) {
            float wt[4][4], wl[4][4];
            for (int kk = 0; kk < 4; kk++) {
                *(float4*)&wt[kk][0] = *(const float4*)(Wa + (k + kk) * D + c4);
                *(float4*)&wl[kk][0] = *(const float4*)(Wb + (k + kk) * D + c4);
            }
            for (int i = 0; i < 4; i++) {
                int gr = row0 + r0 + i;
                if (gr >= N_NODES) gr = N_NODES - 1;   // clamp: safe load
                float a[4], xv[4];
                *(float4*)&a[0]  = *(const float4*)(agg + (size_t)gr * 128 + k);
                *(float4*)&xv[0] = *(const float4*)(x   + (size_t)gr * D + k);
                for (int c = 0; c < 4; c++) {
                    float s = acc[i][c];
                    for (int kk = 0; kk < 4; kk++)
                        s += a[kk] * wt[kk][c] + xv[kk] * wl[kk][c];
                    acc[i][c] = s;
                }
            }
        }
        for (int i = 0; i < 4; i++) {
            int gr = row0 + r0 + i;
            if (gr < N_NODES)
                *(float4*)(out + (size_t)gr * D + c4) = *(float4*)&acc[i][0];
        }
    } else {
        int row0 = (blockIdx.x - NODE_BLOCKS) * 64;
        for (int k = 0; k < D; k += 4) {
            float wt[4][4];
            for (int kk = 0; kk < 4; kk++)
                *(float4*)&wt[kk][0] = *(const float4*)(Wa + (k + kk) * D + c4);
            for (int i = 0; i < 4; i++) {
                int gr = row0 + r0 + i;
                if (gr >= N_REL) gr = N_REL - 1;
                float a[4];
                *(float4*)&a[0] = *(const float4*)(rel + (size_t)gr * D + k);
                for (int c = 0; c < 4; c++) {
                    float s = acc[i][c];
                    for (int kk = 0; kk < 4; kk++)
                        s += a[kk] * wt[kk][c];
                    acc[i][c] = s;
                }
            }
        }
        for (int i = 0; i < 4; i++) {
            int gr = row0 + r0 + i;
            if (gr < N_REL)
                *(float4*)(out + (size_t)(N_NODES + gr) * D + c4) = *(float4*)&acc[i][0];
        }
    }
}

// ---------------------------------------------------------------------------
// Workspace layout (bytes), total 49.8 MB (falls back to 33.0 MB legacy
// single-pass build if ws_size is too small):
//   [0, 200000)            cnt           : N_NODES int  (zeroed)
//   [200000, 200032)       bucket_cursor : NBUCKET int  (zeroed)
//   [200064, 400064)       h_att   : N_NODES fp32
//   [400064, 600064)       t_att   : N_NODES fp32
//   [600064, 602064)       r_att   : N_REL fp32
//   [602064, 606064)       ts_att  : N_TIME fp32
//   [1.0M, 26.6M)          payload : N_NODES*64 int2  -- OVERLAID by agg
//                          agg     : N_NODES rows, stride 128 fp32
//   [26.6M, 33.0M)         x_bf    : N_NODES*64 bf16
//   [33.0M, 49.8M)         stage   : NBUCKET * STAGE_CAP int4
// ---------------------------------------------------------------------------
extern "C" void kernel_launch(void* const* d_in, const int* in_sizes, int n_in,
                              void* d_out, int out_size, void* d_ws, size_t ws_size,
                              hipStream_t stream) {
    const float* x    = (const float*)d_in[0];
    const float* rel  = (const float*)d_in[1];
    const float* tim  = (const float*)d_in[2];
    const int* src   = (const int*)d_in[3];
    const int* dst   = (const int*)d_in[4];
    const int* etype = (const int*)d_in[5];
    const int* etime = (const int*)d_in[6];
    const float* trans_w = (const float*)d_in[7];
    const float* loop_w  = (const float*)d_in[8];
    const float* w_rel   = (const float*)d_in[9];
    const float* ah  = (const float*)d_in[10];
    const float* at  = (const float*)d_in[11];
    const float* ar  = (const float*)d_in[12];
    const float* ats = (const float*)d_in[13];

    char* ws = (char*)d_ws;
    int*   cnt            = (int*)  (ws);
    int*   bucket_cursor  = (int*)  (ws + 200000);
    float* h_att          = (float*)(ws + 200064);
    float* t_att          = (float*)(ws + 400064);
    float* r_att          = (float*)(ws + 600064);
    float* ts_att         = (float*)(ws + 602064);
    int2*  payload        = (int2*) (ws + 1000000);
    float* agg            = (float*)(ws + 1000000);   // overlay, stride 128
    unsigned short* x_bf  = (unsigned short*)(ws + 26600000);
    int4*  stage          = (int4*) (ws + 33000000);

    float* out = (float*)d_out;

    const size_t need = 33000000ull + (size_t)NBUCKET * STAGE_CAP * sizeof(int4);
    const bool two_phase = (ws_size >= need);

    hipMemsetAsync(cnt, 0, 200032, stream);   // cnt + bucket_cursor

    {   // K1: projections + bf16 cast
        int waves = N_NODES + N_REL + N_TIME;
        proj_kernel<<<(waves + 3) / 4, 256, 0, stream>>>(
            x, rel, tim, ah, at, ar, ats,
            h_att, t_att, r_att, ts_att, x_bf);
    }
    if (two_phase) {
        // K2a: coalesced binning into 8 dst-range buckets
        bin_kernel<<<(N_EDGES + TILE - 1) / TILE, 256, 0, stream>>>(
            src, dst, etype, etime, h_att, t_att, r_att, ts_att,
            bucket_cursor, stage);
        // K2b: XCD-local scatter, L2-merged writeback
        scatter_kernel<<<NBUCKET * PASS2_CHUNKS, 256, 0, stream>>>(
            bucket_cursor, stage, cnt, payload);
    } else {
        // Legacy single-pass build
        build_kernel<<<(N_EDGES + 255) / 256, 256, 0, stream>>>(
            src, dst, etype, etime, h_att, t_att, r_att, ts_att, cnt, payload);
    }
    {   // K3: per-node softmax + gather-aggregate
        node_gather_kernel<<<(N_NODES + 3) / 4, 256, 0, stream>>>(
            x_bf, rel, tim, cnt, payload, agg);
    }
    {   // K4: fused epilogue GEMMs (nodes + rels)
        out_gemm_kernel<<<NODE_BLOCKS + REL_BLOCKS, 256, 0, stream>>>(
            agg, x, rel, trans_w, loop_w, w_rel, out);
    }
}

// Round 2
// 214.017 us; speedup vs baseline: 1.0246x; 1.0246x over previous
//
#include <hip/hip_runtime.h>
#include <hip/hip_bf16.h>

#define N_NODES 50000
#define N_EDGES 800000
#define D 64
#define N_REL 500
#define N_TIME 1000
#define SLOTS 64   // legacy per-node payload capacity (fallback path)
#define NODE_BLOCKS ((N_NODES + 63) / 64)   // 782
#define REL_BLOCKS  ((N_REL + 63) / 64)     // 8

// Fused two-phase build parameters
#define CB 128                              // dst-nodes per coarse bucket
#define NCB ((N_NODES + CB - 1) / CB)       // 391 buckets
#define FR 64                               // dst-nodes per fused-K3 block
#define NFB ((N_NODES + FR - 1) / FR)       // 782 blocks
#define SCAP 4096                           // records per bucket (mean ~2048)
#define BINCAP 8                            // LDS bin cap per tile (mean 2.6)
#define BTILE 1024                          // edges per bin block (4/thread)
#define LSLOT 48                            // per-node LDS slot cap (max deg ~35)

__device__ __forceinline__ float bf2f(unsigned short u) {
    union { unsigned int i; float f; } v;
    v.i = ((unsigned int)u) << 16;
    return v.f;
}

// ---------------------------------------------------------------------------
// K1: scalar attention projections + bf16 cast of x.  One wave per row.
// ---------------------------------------------------------------------------
__global__ void proj_kernel(const float* __restrict__ x,
                            const float* __restrict__ rel,
                            const float* __restrict__ tim,
                            const float* __restrict__ ah,
                            const float* __restrict__ at,
                            const float* __restrict__ ar,
                            const float* __restrict__ ats,
                            float* __restrict__ h_att, float* __restrict__ t_att,
                            float* __restrict__ r_att, float* __restrict__ ts_att,
                            unsigned short* __restrict__ x_bf) {
    int wave = (blockIdx.x * blockDim.x + threadIdx.x) >> 6;
    int lane = threadIdx.x & 63;
    const int total = N_NODES + N_REL + N_TIME;
    if (wave >= total) return;
    if (wave < N_NODES) {
        float xv = x[wave * D + lane];
        __hip_bfloat16 b = __float2bfloat16(xv);
        x_bf[wave * D + lane] = *(unsigned short*)&b;
        float s1 = xv * ah[lane];
        float s2 = xv * at[lane];
        for (int off = 32; off; off >>= 1) {
            s1 += __shfl_down(s1, off);
            s2 += __shfl_down(s2, off);
        }
        if (lane == 0) { h_att[wave] = s1; t_att[wave] = s2; }
    } else if (wave < N_NODES + N_REL) {
        int r = wave - N_NODES;
        float v = rel[r * D + lane] * ar[lane];
        for (int off = 32; off; off >>= 1) v += __shfl_down(v, off);
        if (lane == 0) r_att[r] = v;
    } else {
        int t = wave - N_NODES - N_REL;
        float v = tim[t * D + lane] * ats[lane];
        for (int off = 32; off; off >>= 1) v += __shfl_down(v, off);
        if (lane == 0) ts_att[t] = v;
    }
}

// ---------------------------------------------------------------------------
// K2a: bin edges into 391 fine dst-range buckets (128 nodes each) with
// COALESCED run writes.  Record = {pl.x, pl.y, dst, 0} (same bit-packing as
// legacy payload: 3 stolen ex-mantissa bits carry s&7; rel err 8e-7).
// Per 1024-edge tile: LDS bins (mean 2.6/bucket, cap 8) -> one cursor
// atomicAdd per nonempty bucket -> contiguous int4 run flush by the SAME
// thread (no second barrier).  Overflow (~1e-4 of tiles) appends direct.
// ---------------------------------------------------------------------------
__global__ __launch_bounds__(256)
void bin_kernel(const int* __restrict__ src, const int* __restrict__ dst,
                const int* __restrict__ etype, const int* __restrict__ etime,
                const float* __restrict__ h_att, const float* __restrict__ t_att,
                const float* __restrict__ r_att, const float* __restrict__ ts_att,
                int* __restrict__ cursor, int4* __restrict__ stage) {
    __shared__ int4 bins[NCB][BINCAP];   // 391*8*16 = 50048 B
    __shared__ int bcnt[NCB];
    int t = threadIdx.x;
    for (int k = t; k < NCB; k += 256) bcnt[k] = 0;
    __syncthreads();

    int e0 = blockIdx.x * BTILE;
    for (int j = 0; j < 4; j++) {
        int e = e0 + j * 256 + t;
        if (e < N_EDGES) {
            int s = src[e], d = dst[e], r = etype[e], tt = etime[e];
            float lg = h_att[s] - t_att[d] + r_att[r] + ts_att[tt];
            float lr = lg > 0.f ? lg : 0.1f * lg;
            float ex = __expf(lr);
            unsigned exb = __float_as_uint(ex);
            int4 rec;
            rec.x = (int)((exb & ~7u) | (unsigned)(s & 7));
            rec.y = (int)(((unsigned)(s >> 3) << 19) | ((unsigned)r << 10) | (unsigned)tt);
            rec.z = d;
            rec.w = 0;
            int k = d >> 7;                     // CB = 128
            int pos = atomicAdd(&bcnt[k], 1);
            if (pos < BINCAP) {
                bins[k][pos] = rec;
            } else {                            // statistically ~never
                int g = atomicAdd(&cursor[k], 1);
                if (g < SCAP) stage[(size_t)k * SCAP + g] = rec;
            }
        }
    }
    __syncthreads();
    // reserve + flush by the same thread: one cursor atomic per bucket
    for (int k = t; k < NCB; k += 256) {
        int c = bcnt[k];
        if (c > BINCAP) c = BINCAP;
        if (c > 0) {
            int base = atomicAdd(&cursor[k], c);
            for (int i = 0; i < c; i++) {
                int g = base + i;
                if (g < SCAP) stage[(size_t)k * SCAP + g] = bins[k][i];
            }
        }
    }
}

// ---------------------------------------------------------------------------
// K3': fused scatter + softmax + gather.  Block = 64 dst nodes (4 waves).
// Phase 0: read parent bucket's staged records COALESCED (2x re-read, 25.6 MB
// total), filter to this block's 64-node range, slot into LDS per-node lists.
// Phase A/B: exactly the proven K3 (butterfly den + quarter-wave gather) but
// sourcing slots from LDS.  The 50 MB random payload write + read round-trip
// of the legacy path does not exist.  agg is plain stride-64.
// ---------------------------------------------------------------------------
__global__ __launch_bounds__(256)
void node_fused_kernel(const unsigned short* __restrict__ x_bf,
                       const float* __restrict__ rel,
                       const float* __restrict__ tim,
                       const int* __restrict__ cursor,
                       const int4* __restrict__ stage,
                       float* __restrict__ agg) {
    __shared__ int2 lslot[FR * LSLOT];   // 64*48*8 = 24576 B
    __shared__ int lcnt[FR];
    int tid = threadIdx.x;
    int base = blockIdx.x * FR;
    int pb = blockIdx.x >> 1;            // parent bucket (CB = 2*FR)

    for (int i = tid; i < FR; i += 256) lcnt[i] = 0;
    __syncthreads();

    // Phase 0: coalesced bucket read -> LDS slot lists
    int n = cursor[pb];
    if (n > SCAP) n = SCAP;
    for (int i = tid; i < n; i += 256) {
        int4 rec = stage[(size_t)pb * SCAP + i];
        int ln = rec.z - base;
        if ((unsigned)ln < FR) {
            int pos = atomicAdd(&lcnt[ln], 1);
            if (pos < LSLOT) lslot[ln * LSLOT + pos] = make_int2(rec.x, rec.y);
        }
    }
    __syncthreads();

    int lane = tid & 63;
    int wv = tid >> 6;
    int qw = lane >> 4;
    int ql = lane & 15;

    for (int ln = wv; ln < FR; ln += 4) {
        int d = base + ln;
        if (d >= N_NODES) break;
        int deg = lcnt[ln];
        if (deg > LSLOT) deg = LSLOT;

        // Phase A: slot decode + butterfly den
        int s_l = 0, r_l = 0, t_l = 0;
        float ex = 0.f;
        if (lane < deg) {
            int2 pl = lslot[ln * LSLOT + lane];
            unsigned px = (unsigned)pl.x;
            unsigned py = (unsigned)pl.y;
            ex = __uint_as_float(px & ~7u);
            s_l = (int)(((py >> 19) << 3) | (px & 7u));
            r_l = (int)((py >> 10) & 511u);
            t_l = (int)(py & 1023u);
        }
        float den = ex;
        for (int off = 32; off; off >>= 1) den += __shfl_xor(den, off);
        float att_l = (lane < deg) ? ex / den : 0.f;

        // Phase B: quarter-wave per edge
        float4 acc = make_float4(0.f, 0.f, 0.f, 0.f);
        for (int i = 0; i < deg; i += 4) {
            int ei = i + qw;                  // < 64 always
            int s = __shfl(s_l, ei);
            int r = __shfl(r_l, ei);
            int t = __shfl(t_l, ei);
            float att = __shfl(att_l, ei);    // 0 if ei >= deg
            float4  te = *(const float4*)(tim + t * D + ql * 4);
            ushort4 xb = *(const ushort4*)(x_bf + s * D + ql * 4);
            float4  rl = *(const float4*)(rel + r * D + ql * 4);
            acc.x += att * (bf2f(xb.x) + te.x) * (rl.x + te.x);
            acc.y += att * (bf2f(xb.y) + te.y) * (rl.y + te.y);
            acc.z += att * (bf2f(xb.z) + te.z) * (rl.z + te.z);
            acc.w += att * (bf2f(xb.w) + te.w) * (rl.w + te.w);
        }
        for (int off = 16; off <= 32; off <<= 1) {
            acc.x += __shfl_xor(acc.x, off);
            acc.y += __shfl_xor(acc.y, off);
            acc.z += __shfl_xor(acc.z, off);
            acc.w += __shfl_xor(acc.w, off);
        }
        if (qw == 0)
            *(float4*)(agg + (size_t)d * D + ql * 4) = acc;   // stride 64
    }
}

// ---------------------------------------------------------------------------
// Legacy fallback kernels (R0-proven 207 us path), used if ws too small.
// ---------------------------------------------------------------------------
__global__ void build_kernel(const int* __restrict__ src, const int* __restrict__ dst,
                             const int* __restrict__ etype, const int* __restrict__ etime,
                             const float* __restrict__ h_att, const float* __restrict__ t_att,
                             const float* __restrict__ r_att, const float* __restrict__ ts_att,
                             int* __restrict__ cnt, int2* __restrict__ payload) {
    int e = blockIdx.x * blockDim.x + threadIdx.x;
    if (e >= N_EDGES) return;
    int s = src[e], d = dst[e], r = etype[e], t = etime[e];
    float lg = h_att[s] - t_att[d] + r_att[r] + ts_att[t];
    float lr = lg > 0.f ? lg : 0.1f * lg;
    float ex = __expf(lr);
    unsigned exb = __float_as_uint(ex);
    int2 pl;
    pl.x = (int)((exb & ~7u) | (unsigned)(s & 7));
    pl.y = (int)(((unsigned)(s >> 3) << 19) | ((unsigned)r << 10) | (unsigned)t);
    int pos = atomicAdd(&cnt[d], 1);
    if (pos < SLOTS) payload[(d << 6) + pos] = pl;
}

__global__ void node_gather_kernel(const unsigned short* __restrict__ x_bf,
                                   const float* __restrict__ rel,
                                   const float* __restrict__ tim,
                                   const int* __restrict__ cnt,
                                   const int2* __restrict__ payload,
                                   float* __restrict__ agg) {
    int d = (blockIdx.x * blockDim.x + threadIdx.x) >> 6;
    int lane = threadIdx.x & 63;
    if (d >= N_NODES) return;
    int deg = cnt[d];
    if (deg > SLOTS) deg = SLOTS;
    int s_l = 0, r_l = 0, t_l = 0;
    float ex = 0.f;
    if (lane < deg) {
        int2 pl = payload[(d << 6) + lane];
        unsigned px = (unsigned)pl.x;
        unsigned py = (unsigned)pl.y;
        ex = __uint_as_float(px & ~7u);
        s_l = (int)(((py >> 19) << 3) | (px & 7u));
        r_l = (int)((py >> 10) & 511u);
        t_l = (int)(py & 1023u);
    }
    float den = ex;
    for (int off = 32; off; off >>= 1) den += __shfl_xor(den, off);
    float att_l = (lane < deg) ? ex / den : 0.f;
    int qw = lane >> 4;
    int ql = lane & 15;
    float4 acc = make_float4(0.f, 0.f, 0.f, 0.f);
    for (int i = 0; i < deg; i += 4) {
        int ei = i + qw;
        int s = __shfl(s_l, ei);
        int r = __shfl(r_l, ei);
        int t = __shfl(t_l, ei);
        float att = __shfl(att_l, ei);
        float4  te = *(const float4*)(tim + t * D + ql * 4);
        ushort4 xb = *(const ushort4*)(x_bf + s * D + ql * 4);
        float4  rl = *(const float4*)(rel + r * D + ql * 4);
        acc.x += att * (bf2f(xb.x) + te.x) * (rl.x + te.x);
        acc.y += att * (bf2f(xb.y) + te.y) * (rl.y + te.y);
        acc.z += att * (bf2f(xb.z) + te.z) * (rl.z + te.z);
        acc.w += att * (bf2f(xb.w) + te.w) * (rl.w + te.w);
    }
    for (int off = 16; off <= 32; off <<= 1) {
        acc.x += __shfl_xor(acc.x, off);
        acc.y += __shfl_xor(acc.y, off);
        acc.z += __shfl_xor(acc.z, off);
        acc.w += __shfl_xor(acc.w, off);
    }
    if (qw == 0)
        *(float4*)(agg + (d << 7) + ql * 4) = acc;   // stride 128 (overlay)
}

// ---------------------------------------------------------------------------
// K4: epilogue GEMMs, register-blocked 4x4 per thread, 64-row tiles.
// astride = agg row stride in floats (64 fused path, 128 legacy overlay).
// ---------------------------------------------------------------------------
__global__ __launch_bounds__(256, 4)
void out_gemm_kernel(const float* __restrict__ agg,
                     const float* __restrict__ x,
                     const float* __restrict__ rel,
                     const float* __restrict__ trans_w,
                     const float* __restrict__ loop_w,
                     const float* __restrict__ w_rel,
                     float* __restrict__ out, int astride) {
    __shared__ float Wa[D * D];
    __shared__ float Wb[D * D];
    int t = threadIdx.x;
    bool nodeb = blockIdx.x < NODE_BLOCKS;

    for (int j = 0; j < 4; j++) {
        int idx = (t + 256 * j) * 4;
        if (nodeb) {
            *(float4*)(Wa + idx) = *(const float4*)(trans_w + idx);
            *(float4*)(Wb + idx) = *(const float4*)(loop_w + idx);
        } else {
            *(float4*)(Wa + idx) = *(const float4*)(w_rel + idx);
        }
    }
    __syncthreads();

    int lane = t & 63;
    int wv = t >> 6;
    int c4 = (lane & 15) << 2;
    int r0 = wv * 16 + (lane >> 4) * 4;

    float acc[4][4];
    for (int i = 0; i < 4; i++)
        for (int c = 0; c < 4; c++) acc[i][c] = 0.f;

    if (nodeb) {
        int row0 = blockIdx.x * 64;
        for (int k = 0; k < D; k += 4) {
            float wt[4][4], wl[4][4];
            for (int kk = 0; kk < 4; kk++) {
                *(float4*)&wt[kk][0] = *(const float4*)(Wa + (k + kk) * D + c4);
                *(float4*)&wl[kk][0] = *(const float4*)(Wb + (k + kk) * D + c4);
            }
            for (int i = 0; i < 4; i++) {
                int gr = row0 + r0 + i;
                if (gr >= N_NODES) gr = N_NODES - 1;   // clamp: safe load
                float a[4], xv[4];
                *(float4*)&a[0]  = *(const float4*)(agg + (size_t)gr * astride + k);
                *(float4*)&xv[0] = *(const float4*)(x   + (size_t)gr * D + k);
                for (int c = 0; c < 4; c++) {
                    float s = acc[i][c];
                    for (int kk = 0; kk < 4; kk++)
                        s += a[kk] * wt[kk][c] + xv[kk] * wl[kk][c];
                    acc[i][c] = s;
                }
            }
        }
        for (int i = 0; i < 4; i++) {
            int gr = row0 + r0 + i;
            if (gr < N_NODES)
                *(float4*)(out + (size_t)gr * D + c4) = *(float4*)&acc[i][0];
        }
    } else {
        int row0 = (blockIdx.x - NODE_BLOCKS) * 64;
        for (int k = 0; k < D; k += 4) {
            float wt[4][4];
            for (int kk = 0; kk < 4; kk++)
                *(float4*)&wt[kk][0] = *(const float4*)(Wa + (k + kk) * D + c4);
            for (int i = 0; i < 4; i++) {
                int gr = row0 + r0 + i;
                if (gr >= N_REL) gr = N_REL - 1;
                float a[4];
                *(float4*)&a[0] = *(const float4*)(rel + (size_t)gr * D + k);
                for (int c = 0; c < 4; c++) {
                    float s = acc[i][c];
                    for (int kk = 0; kk < 4; kk++)
                        s += a[kk] * wt[kk][c];
                    acc[i][c] = s;
                }
            }
        }
        for (int i = 0; i < 4; i++) {
            int gr = row0 + r0 + i;
            if (gr < N_REL)
                *(float4*)(out + (size_t)(N_NODES + gr) * D + c4) = *(float4*)&acc[i][0];
        }
    }
}

// ---------------------------------------------------------------------------
// Workspace layout (bytes), total 58.7 MB (fused path):
//   [0, 200000)       cursor (391 int, fused) / cnt (50000 int, legacy) -- zeroed
//   [200064, 400064)  h_att   : N_NODES fp32
//   [400064, 600064)  t_att   : N_NODES fp32
//   [600064, 602064)  r_att   : N_REL fp32
//   [602064, 606064)  ts_att  : N_TIME fp32
//   [1.0M, 13.8M)     agg     : N_NODES x 64 fp32 (fused)   |  legacy: payload
//                     overlay [1.0M, 26.6M) stride-128 agg
//   [26.6M, 33.0M)    x_bf    : N_NODES*64 bf16
//   [33.0M, 58.7M)    stage   : NCB * SCAP int4 (fused only)
// ---------------------------------------------------------------------------
extern "C" void kernel_launch(void* const* d_in, const int* in_sizes, int n_in,
                              void* d_out, int out_size, void* d_ws, size_t ws_size,
                              hipStream_t stream) {
    const float* x    = (const float*)d_in[0];
    const float* rel  = (const float*)d_in[1];
    const float* tim  = (const float*)d_in[2];
    const int* src   = (const int*)d_in[3];
    const int* dst   = (const int*)d_in[4];
    const int* etype = (const int*)d_in[5];
    const int* etime = (const int*)d_in[6];
    const float* trans_w = (const float*)d_in[7];
    const float* loop_w  = (const float*)d_in[8];
    const float* w_rel   = (const float*)d_in[9];
    const float* ah  = (const float*)d_in[10];
    const float* at  = (const float*)d_in[11];
    const float* ar  = (const float*)d_in[12];
    const float* ats = (const float*)d_in[13];

    char* ws = (char*)d_ws;
    int*   cursor         = (int*)  (ws);            // fused path
    int*   cnt            = (int*)  (ws);            // legacy path
    float* h_att          = (float*)(ws + 200064);
    float* t_att          = (float*)(ws + 400064);
    float* r_att          = (float*)(ws + 600064);
    float* ts_att         = (float*)(ws + 602064);
    float* agg            = (float*)(ws + 1000000);
    int2*  payload        = (int2*) (ws + 1000000);  // legacy overlay
    unsigned short* x_bf  = (unsigned short*)(ws + 26600000);
    int4*  stage          = (int4*) (ws + 33000000);

    float* out = (float*)d_out;

    const size_t need = 33000000ull + (size_t)NCB * SCAP * sizeof(int4);
    const bool fused = (ws_size >= need);

    hipMemsetAsync(ws, 0, 200000, stream);   // cursor / cnt

    {   // K1: projections + bf16 cast
        int waves = N_NODES + N_REL + N_TIME;
        proj_kernel<<<(waves + 3) / 4, 256, 0, stream>>>(
            x, rel, tim, ah, at, ar, ats,
            h_att, t_att, r_att, ts_att, x_bf);
    }
    if (fused) {
        // K2a: coalesced fine-bucket binning (391 buckets x 128 nodes)
        bin_kernel<<<(N_EDGES + BTILE - 1) / BTILE, 256, 0, stream>>>(
            src, dst, etype, etime, h_att, t_att, r_att, ts_att,
            cursor, stage);
        // K3': fused LDS scatter + softmax + gather (no payload round-trip)
        node_fused_kernel<<<NFB, 256, 0, stream>>>(
            x_bf, rel, tim, cursor, stage, agg);
        // K4: epilogue GEMMs, agg stride 64
        out_gemm_kernel<<<NODE_BLOCKS + REL_BLOCKS, 256, 0, stream>>>(
            agg, x, rel, trans_w, loop_w, w_rel, out, 64);
    } else {
        // Legacy R0 path
        build_kernel<<<(N_EDGES + 255) / 256, 256, 0, stream>>>(
            src, dst, etype, etime, h_att, t_att, r_att, ts_att, cnt, payload);
        node_gather_kernel<<<(N_NODES + 3) / 4, 256, 0, stream>>>(
            x_bf, rel, tim, cnt, payload, agg);
        out_gemm_kernel<<<NODE_BLOCKS + REL_BLOCKS, 256, 0, stream>>>(
            agg, x, rel, trans_w, loop_w, w_rel, out, 128);
    }
}

// Round 3
// 209.342 us; speedup vs baseline: 1.0475x; 1.0223x over previous
//
#include <hip/hip_runtime.h>
#include <hip/hip_bf16.h>

#define N_NODES 50000
#define N_EDGES 800000
#define D 64
#define N_REL 500
#define N_TIME 1000
#define SLOTS 64   // legacy per-node payload capacity (fallback path)
#define NODE_BLOCKS ((N_NODES + 63) / 64)   // 782
#define REL_BLOCKS  ((N_REL + 63) / 64)     // 8

// Fused two-phase build parameters (R3: CB == FR, 512-thread blocks)
#define CB 64                               // dst-nodes per bucket == FR (1x re-read)
#define NCB ((N_NODES + CB - 1) / CB)       // 782 buckets
#define FR 64                               // dst-nodes per fused-K3 block
#define NFB ((N_NODES + FR - 1) / FR)       // 782 blocks
#define SCAP 2048                           // records per bucket (mean 1024, +32 sigma)
#define BINCAP 4                            // LDS bin cap per tile (lambda 1.31)
#define BTILE 1024                          // edges per bin block (2/thread @ 512)
#define LSLOT 48                            // per-node LDS slot cap (max deg ~35)

__device__ __forceinline__ float bf2f(unsigned short u) {
    union { unsigned int i; float f; } v;
    v.i = ((unsigned int)u) << 16;
    return v.f;
}

// ---------------------------------------------------------------------------
// K1: scalar attention projections + bf16 cast of x.  One wave per row.
// ---------------------------------------------------------------------------
__global__ void proj_kernel(const float* __restrict__ x,
                            const float* __restrict__ rel,
                            const float* __restrict__ tim,
                            const float* __restrict__ ah,
                            const float* __restrict__ at,
                            const float* __restrict__ ar,
                            const float* __restrict__ ats,
                            float* __restrict__ h_att, float* __restrict__ t_att,
                            float* __restrict__ r_att, float* __restrict__ ts_att,
                            unsigned short* __restrict__ x_bf) {
    int wave = (blockIdx.x * blockDim.x + threadIdx.x) >> 6;
    int lane = threadIdx.x & 63;
    const int total = N_NODES + N_REL + N_TIME;
    if (wave >= total) return;
    if (wave < N_NODES) {
        float xv = x[wave * D + lane];
        __hip_bfloat16 b = __float2bfloat16(xv);
        x_bf[wave * D + lane] = *(unsigned short*)&b;
        float s1 = xv * ah[lane];
        float s2 = xv * at[lane];
        for (int off = 32; off; off >>= 1) {
            s1 += __shfl_down(s1, off);
            s2 += __shfl_down(s2, off);
        }
        if (lane == 0) { h_att[wave] = s1; t_att[wave] = s2; }
    } else if (wave < N_NODES + N_REL) {
        int r = wave - N_NODES;
        float v = rel[r * D + lane] * ar[lane];
        for (int off = 32; off; off >>= 1) v += __shfl_down(v, off);
        if (lane == 0) r_att[r] = v;
    } else {
        int t = wave - N_NODES - N_REL;
        float v = tim[t * D + lane] * ats[lane];
        for (int off = 32; off; off >>= 1) v += __shfl_down(v, off);
        if (lane == 0) ts_att[t] = v;
    }
}

// ---------------------------------------------------------------------------
// K2a: bin edges into 782 fine dst-range buckets (64 nodes each) with
// COALESCED run writes.  Record = {pl.x, pl.y, dst, 0} (payload bit-packing:
// 3 stolen ex-mantissa bits carry s&7; rel err 8e-7).
// 512 threads, 2 edges/thread.  LDS bins (lambda 1.31/bucket, cap 4) ->
// one cursor atomicAdd per nonempty bucket -> contiguous run flush.
// Overflow (~1% of edges) appends direct (uncoalesced but correct).
// ---------------------------------------------------------------------------
__global__ __launch_bounds__(512)
void bin_kernel(const int* __restrict__ src, const int* __restrict__ dst,
                const int* __restrict__ etype, const int* __restrict__ etime,
                const float* __restrict__ h_att, const float* __restrict__ t_att,
                const float* __restrict__ r_att, const float* __restrict__ ts_att,
                int* __restrict__ cursor, int4* __restrict__ stage) {
    __shared__ int4 bins[NCB][BINCAP];   // 782*4*16 = 50048 B
    __shared__ int bcnt[NCB];            // 3128 B
    int t = threadIdx.x;
    for (int k = t; k < NCB; k += 512) bcnt[k] = 0;
    __syncthreads();

    int e0 = blockIdx.x * BTILE;
    for (int j = 0; j < 2; j++) {
        int e = e0 + j * 512 + t;
        if (e < N_EDGES) {
            int s = src[e], d = dst[e], r = etype[e], tt = etime[e];
            float lg = h_att[s] - t_att[d] + r_att[r] + ts_att[tt];
            float lr = lg > 0.f ? lg : 0.1f * lg;
            float ex = __expf(lr);
            unsigned exb = __float_as_uint(ex);
            int4 rec;
            rec.x = (int)((exb & ~7u) | (unsigned)(s & 7));
            rec.y = (int)(((unsigned)(s >> 3) << 19) | ((unsigned)r << 10) | (unsigned)tt);
            rec.z = d;
            rec.w = 0;
            int k = d >> 6;                     // CB = 64
            int pos = atomicAdd(&bcnt[k], 1);
            if (pos < BINCAP) {
                bins[k][pos] = rec;
            } else {                            // ~1% of edges
                int g = atomicAdd(&cursor[k], 1);
                if (g < SCAP) stage[(size_t)k * SCAP + g] = rec;
            }
        }
    }
    __syncthreads();
    // reserve + flush by the same thread: one cursor atomic per bucket
    for (int k = t; k < NCB; k += 512) {
        int c = bcnt[k];
        if (c > BINCAP) c = BINCAP;
        if (c > 0) {
            int base = atomicAdd(&cursor[k], c);
            for (int i = 0; i < c; i++) {
                int g = base + i;
                if (g < SCAP) stage[(size_t)k * SCAP + g] = bins[k][i];
            }
        }
    }
}

// ---------------------------------------------------------------------------
// K3': fused scatter + softmax + gather.  Block = 64 dst nodes, 512 threads
// (8 waves x 8 nodes).  Phase 0: read OWN bucket's staged records COALESCED
// (CB==FR: exactly 1x, 12.8 MB total), slot into LDS per-node lists.
// Phase A/B: proven butterfly den + quarter-wave gather from LDS slots.
// 8 waves/block x ~3 blocks/CU = ~24 waves/CU to hide gather latency
// (R2 at 4 waves/block measured 26.7% occupancy, latency-bound).
// ---------------------------------------------------------------------------
__global__ __launch_bounds__(512)
void node_fused_kernel(const unsigned short* __restrict__ x_bf,
                       const float* __restrict__ rel,
                       const float* __restrict__ tim,
                       const int* __restrict__ cursor,
                       const int4* __restrict__ stage,
                       float* __restrict__ agg) {
    __shared__ int2 lslot[FR * LSLOT];   // 64*48*8 = 24576 B
    __shared__ int lcnt[FR];
    int tid = threadIdx.x;
    int base = blockIdx.x * FR;
    int pb = blockIdx.x;                 // own bucket (CB == FR)

    for (int i = tid; i < FR; i += 512) lcnt[i] = 0;
    __syncthreads();

    // Phase 0: coalesced bucket read -> LDS slot lists
    int n = cursor[pb];
    if (n > SCAP) n = SCAP;
    for (int i = tid; i < n; i += 512) {
        int4 rec = stage[(size_t)pb * SCAP + i];
        int ln = rec.z - base;
        if ((unsigned)ln < FR) {
            int pos = atomicAdd(&lcnt[ln], 1);
            if (pos < LSLOT) lslot[ln * LSLOT + pos] = make_int2(rec.x, rec.y);
        }
    }
    __syncthreads();

    int lane = tid & 63;
    int wv = tid >> 6;                   // 0..7
    int qw = lane >> 4;
    int ql = lane & 15;

    for (int ln = wv; ln < FR; ln += 8) {
        int d = base + ln;
        if (d >= N_NODES) break;
        int deg = lcnt[ln];
        if (deg > LSLOT) deg = LSLOT;

        // Phase A: slot decode + butterfly den
        int s_l = 0, r_l = 0, t_l = 0;
        float ex = 0.f;
        if (lane < deg) {
            int2 pl = lslot[ln * LSLOT + lane];
            unsigned px = (unsigned)pl.x;
            unsigned py = (unsigned)pl.y;
            ex = __uint_as_float(px & ~7u);
            s_l = (int)(((py >> 19) << 3) | (px & 7u));
            r_l = (int)((py >> 10) & 511u);
            t_l = (int)(py & 1023u);
        }
        float den = ex;
        for (int off = 32; off; off >>= 1) den += __shfl_xor(den, off);
        float att_l = (lane < deg) ? ex / den : 0.f;

        // Phase B: quarter-wave per edge
        float4 acc = make_float4(0.f, 0.f, 0.f, 0.f);
        for (int i = 0; i < deg; i += 4) {
            int ei = i + qw;                  // < 64 always
            int s = __shfl(s_l, ei);
            int r = __shfl(r_l, ei);
            int t = __shfl(t_l, ei);
            float att = __shfl(att_l, ei);    // 0 if ei >= deg
            float4  te = *(const float4*)(tim + t * D + ql * 4);
            ushort4 xb = *(const ushort4*)(x_bf + s * D + ql * 4);
            float4  rl = *(const float4*)(rel + r * D + ql * 4);
            acc.x += att * (bf2f(xb.x) + te.x) * (rl.x + te.x);
            acc.y += att * (bf2f(xb.y) + te.y) * (rl.y + te.y);
            acc.z += att * (bf2f(xb.z) + te.z) * (rl.z + te.z);
            acc.w += att * (bf2f(xb.w) + te.w) * (rl.w + te.w);
        }
        for (int off = 16; off <= 32; off <<= 1) {
            acc.x += __shfl_xor(acc.x, off);
            acc.y += __shfl_xor(acc.y, off);
            acc.z += __shfl_xor(acc.z, off);
            acc.w += __shfl_xor(acc.w, off);
        }
        if (qw == 0)
            *(float4*)(agg + (size_t)d * D + ql * 4) = acc;   // stride 64
    }
}

// ---------------------------------------------------------------------------
// Legacy fallback kernels (R0-proven 207 us path), used if ws too small.
// ---------------------------------------------------------------------------
__global__ void build_kernel(const int* __restrict__ src, const int* __restrict__ dst,
                             const int* __restrict__ etype, const int* __restrict__ etime,
                             const float* __restrict__ h_att, const float* __restrict__ t_att,
                             const float* __restrict__ r_att, const float* __restrict__ ts_att,
                             int* __restrict__ cnt, int2* __restrict__ payload) {
    int e = blockIdx.x * blockDim.x + threadIdx.x;
    if (e >= N_EDGES) return;
    int s = src[e], d = dst[e], r = etype[e], t = etime[e];
    float lg = h_att[s] - t_att[d] + r_att[r] + ts_att[t];
    float lr = lg > 0.f ? lg : 0.1f * lg;
    float ex = __expf(lr);
    unsigned exb = __float_as_uint(ex);
    int2 pl;
    pl.x = (int)((exb & ~7u) | (unsigned)(s & 7));
    pl.y = (int)(((unsigned)(s >> 3) << 19) | ((unsigned)r << 10) | (unsigned)t);
    int pos = atomicAdd(&cnt[d], 1);
    if (pos < SLOTS) payload[(d << 6) + pos] = pl;
}

__global__ void node_gather_kernel(const unsigned short* __restrict__ x_bf,
                                   const float* __restrict__ rel,
                                   const float* __restrict__ tim,
                                   const int* __restrict__ cnt,
                                   const int2* __restrict__ payload,
                                   float* __restrict__ agg) {
    int d = (blockIdx.x * blockDim.x + threadIdx.x) >> 6;
    int lane = threadIdx.x & 63;
    if (d >= N_NODES) return;
    int deg = cnt[d];
    if (deg > SLOTS) deg = SLOTS;
    int s_l = 0, r_l = 0, t_l = 0;
    float ex = 0.f;
    if (lane < deg) {
        int2 pl = payload[(d << 6) + lane];
        unsigned px = (unsigned)pl.x;
        unsigned py = (unsigned)pl.y;
        ex = __uint_as_float(px & ~7u);
        s_l = (int)(((py >> 19) << 3) | (px & 7u));
        r_l = (int)((py >> 10) & 511u);
        t_l = (int)(py & 1023u);
    }
    float den = ex;
    for (int off = 32; off; off >>= 1) den += __shfl_xor(den, off);
    float att_l = (lane < deg) ? ex / den : 0.f;
    int qw = lane >> 4;
    int ql = lane & 15;
    float4 acc = make_float4(0.f, 0.f, 0.f, 0.f);
    for (int i = 0; i < deg; i += 4) {
        int ei = i + qw;
        int s = __shfl(s_l, ei);
        int r = __shfl(r_l, ei);
        int t = __shfl(t_l, ei);
        float att = __shfl(att_l, ei);
        float4  te = *(const float4*)(tim + t * D + ql * 4);
        ushort4 xb = *(const ushort4*)(x_bf + s * D + ql * 4);
        float4  rl = *(const float4*)(rel + r * D + ql * 4);
        acc.x += att * (bf2f(xb.x) + te.x) * (rl.x + te.x);
        acc.y += att * (bf2f(xb.y) + te.y) * (rl.y + te.y);
        acc.z += att * (bf2f(xb.z) + te.z) * (rl.z + te.z);
        acc.w += att * (bf2f(xb.w) + te.w) * (rl.w + te.w);
    }
    for (int off = 16; off <= 32; off <<= 1) {
        acc.x += __shfl_xor(acc.x, off);
        acc.y += __shfl_xor(acc.y, off);
        acc.z += __shfl_xor(acc.z, off);
        acc.w += __shfl_xor(acc.w, off);
    }
    if (qw == 0)
        *(float4*)(agg + (d << 7) + ql * 4) = acc;   // stride 128 (overlay)
}

// ---------------------------------------------------------------------------
// K4: epilogue GEMMs, register-blocked 4x4 per thread, 64-row tiles.
// astride = agg row stride in floats (64 fused path, 128 legacy overlay).
// ---------------------------------------------------------------------------
__global__ __launch_bounds__(256, 4)
void out_gemm_kernel(const float* __restrict__ agg,
                     const float* __restrict__ x,
                     const float* __restrict__ rel,
                     const float* __restrict__ trans_w,
                     const float* __restrict__ loop_w,
                     const float* __restrict__ w_rel,
                     float* __restrict__ out, int astride) {
    __shared__ float Wa[D * D];
    __shared__ float Wb[D * D];
    int t = threadIdx.x;
    bool nodeb = blockIdx.x < NODE_BLOCKS;

    for (int j = 0; j < 4; j++) {
        int idx = (t + 256 * j) * 4;
        if (nodeb) {
            *(float4*)(Wa + idx) = *(const float4*)(trans_w + idx);
            *(float4*)(Wb + idx) = *(const float4*)(loop_w + idx);
        } else {
            *(float4*)(Wa + idx) = *(const float4*)(w_rel + idx);
        }
    }
    __syncthreads();

    int lane = t & 63;
    int wv = t >> 6;
    int c4 = (lane & 15) << 2;
    int r0 = wv * 16 + (lane >> 4) * 4;

    float acc[4][4];
    for (int i = 0; i < 4; i++)
        for (int c = 0; c < 4; c++) acc[i][c] = 0.f;

    if (nodeb) {
        int row0 = blockIdx.x * 64;
        for (int k = 0; k < D; k += 4) {
            float wt[4][4], wl[4][4];
            for (int kk = 0; kk < 4; kk++) {
                *(float4*)&wt[kk][0] = *(const float4*)(Wa + (k + kk) * D + c4);
                *(float4*)&wl[kk][0] = *(const float4*)(Wb + (k + kk) * D + c4);
            }
            for (int i = 0; i < 4; i++) {
                int gr = row0 + r0 + i;
                if (gr >= N_NODES) gr = N_NODES - 1;   // clamp: safe load
                float a[4], xv[4];
                *(float4*)&a[0]  = *(const float4*)(agg + (size_t)gr * astride + k);
                *(float4*)&xv[0] = *(const float4*)(x   + (size_t)gr * D + k);
                for (int c = 0; c < 4; c++) {
                    float s = acc[i][c];
                    for (int kk = 0; kk < 4; kk++)
                        s += a[kk] * wt[kk][c] + xv[kk] * wl[kk][c];
                    acc[i][c] = s;
                }
            }
        }
        for (int i = 0; i < 4; i++) {
            int gr = row0 + r0 + i;
            if (gr < N_NODES)
                *(float4*)(out + (size_t)gr * D + c4) = *(float4*)&acc[i][0];
        }
    } else {
        int row0 = (blockIdx.x - NODE_BLOCKS) * 64;
        for (int k = 0; k < D; k += 4) {
            float wt[4][4];
            for (int kk = 0; kk < 4; kk++)
                *(float4*)&wt[kk][0] = *(const float4*)(Wa + (k + kk) * D + c4);
            for (int i = 0; i < 4; i++) {
                int gr = row0 + r0 + i;
                if (gr >= N_REL) gr = N_REL - 1;
                float a[4];
                *(float4*)&a[0] = *(const float4*)(rel + (size_t)gr * D + k);
                for (int c = 0; c < 4; c++) {
                    float s = acc[i][c];
                    for (int kk = 0; kk < 4; kk++)
                        s += a[kk] * wt[kk][c];
                    acc[i][c] = s;
                }
            }
        }
        for (int i = 0; i < 4; i++) {
            int gr = row0 + r0 + i;
            if (gr < N_REL)
                *(float4*)(out + (size_t)(N_NODES + gr) * D + c4) = *(float4*)&acc[i][0];
        }
    }
}

// ---------------------------------------------------------------------------
// Workspace layout (bytes), total 58.6 MB (fused path):
//   [0, 200000)       cursor (782 int, fused) / cnt (50000 int, legacy) -- zeroed
//   [200064, 400064)  h_att   : N_NODES fp32
//   [400064, 600064)  t_att   : N_NODES fp32
//   [600064, 602064)  r_att   : N_REL fp32
//   [602064, 606064)  ts_att  : N_TIME fp32
//   [1.0M, 13.8M)     agg     : N_NODES x 64 fp32 (fused)   |  legacy: payload
//                     overlay [1.0M, 26.6M) stride-128 agg
//   [26.6M, 33.0M)    x_bf    : N_NODES*64 bf16
//   [33.0M, 58.6M)    stage   : NCB * SCAP int4 (fused only)
// ---------------------------------------------------------------------------
extern "C" void kernel_launch(void* const* d_in, const int* in_sizes, int n_in,
                              void* d_out, int out_size, void* d_ws, size_t ws_size,
                              hipStream_t stream) {
    const float* x    = (const float*)d_in[0];
    const float* rel  = (const float*)d_in[1];
    const float* tim  = (const float*)d_in[2];
    const int* src   = (const int*)d_in[3];
    const int* dst   = (const int*)d_in[4];
    const int* etype = (const int*)d_in[5];
    const int* etime = (const int*)d_in[6];
    const float* trans_w = (const float*)d_in[7];
    const float* loop_w  = (const float*)d_in[8];
    const float* w_rel   = (const float*)d_in[9];
    const float* ah  = (const float*)d_in[10];
    const float* at  = (const float*)d_in[11];
    const float* ar  = (const float*)d_in[12];
    const float* ats = (const float*)d_in[13];

    char* ws = (char*)d_ws;
    int*   cursor         = (int*)  (ws);            // fused path
    int*   cnt            = (int*)  (ws);            // legacy path
    float* h_att          = (float*)(ws + 200064);
    float* t_att          = (float*)(ws + 400064);
    float* r_att          = (float*)(ws + 600064);
    float* ts_att         = (float*)(ws + 602064);
    float* agg            = (float*)(ws + 1000000);
    int2*  payload        = (int2*) (ws + 1000000);  // legacy overlay
    unsigned short* x_bf  = (unsigned short*)(ws + 26600000);
    int4*  stage          = (int4*) (ws + 33000000);

    float* out = (float*)d_out;

    const size_t need = 33000000ull + (size_t)NCB * SCAP * sizeof(int4);
    const bool fused = (ws_size >= need);

    hipMemsetAsync(ws, 0, 200000, stream);   // cursor / cnt

    {   // K1: projections + bf16 cast
        int waves = N_NODES + N_REL + N_TIME;
        proj_kernel<<<(waves + 3) / 4, 256, 0, stream>>>(
            x, rel, tim, ah, at, ar, ats,
            h_att, t_att, r_att, ts_att, x_bf);
    }
    if (fused) {
        // K2a: coalesced fine-bucket binning (782 buckets x 64 nodes)
        bin_kernel<<<(N_EDGES + BTILE - 1) / BTILE, 512, 0, stream>>>(
            src, dst, etype, etime, h_att, t_att, r_att, ts_att,
            cursor, stage);
        // K3': fused LDS scatter + softmax + gather, 8 waves/block
        node_fused_kernel<<<NFB, 512, 0, stream>>>(
            x_bf, rel, tim, cursor, stage, agg);
        // K4: epilogue GEMMs, agg stride 64
        out_gemm_kernel<<<NODE_BLOCKS + REL_BLOCKS, 256, 0, stream>>>(
            agg, x, rel, trans_w, loop_w, w_rel, out, 64);
    } else {
        // Legacy R0 path
        build_kernel<<<(N_EDGES + 255) / 256, 256, 0, stream>>>(
            src, dst, etype, etime, h_att, t_att, r_att, ts_att, cnt, payload);
        node_gather_kernel<<<(N_NODES + 3) / 4, 256, 0, stream>>>(
            x_bf, rel, tim, cnt, payload, agg);
        out_gemm_kernel<<<NODE_BLOCKS + REL_BLOCKS, 256, 0, stream>>>(
            agg, x, rel, trans_w, loop_w, w_rel, out, 128);
    }
}